// Round 4
// baseline (381.383 us; speedup 1.0000x reference)
//
#include <hip/hip_runtime.h>
#include <math.h>

// Region-layer loss (YOLOv2 style), MI355X.
// output (32, 425, 76, 76) f32 ; target (32, 250) f32 ; out: scalar f32.
#define NBATCH 32
#define NANCH  5
#define NCLS   80
#define NHH    76
#define NWW    76
#define MAXOBJ 50
#define CSZ    (NHH*NWW)            // 5776
#define CELLS_PER_B (NANCH*CSZ)     // 28880
#define NCH    (5+NCLS)             // 85
#define BLK    256
#define CPT    8                    // cells per thread: two aligned 4-cell groups
#define CPB    (BLK*CPT)            // 2048 cells per block
#define NCBLK  ((CELLS_PER_B + CPB - 1)/CPB)   // 15 cell blocks per batch item
#define GX     (NCBLK + MAXOBJ)     // 65 blocks in x
#define NTOT   (GX*NBATCH)          // 2080 partial-sum slots

// ANCHORS_PX / 32
__constant__ float c_aw[NANCH] = {18.3274f/32.0f, 59.9827f/32.0f, 106.8298f/32.0f, 252.2502f/32.0f, 312.6566f/32.0f};
__constant__ float c_ah[NANCH] = {21.6763f/32.0f, 66.0010f/32.0f, 175.1789f/32.0f, 112.8890f/32.0f, 293.3850f/32.0f};

__device__ __forceinline__ float sigf(float x) { return 1.0f / (1.0f + __expf(-x)); }

// ---------------------------------------------------------------------------
// Fused kernel. grid = (GX, NBATCH), block = 256. Every block writes its
// partial sum to acc[blockIdx.y*GX + blockIdx.x] (no atomics, no memset).
//   blockIdx.x <  NCBLK : cell path — no-object conf loss over 2048 cells
//   blockIdx.x >= NCBLK : obj path  — one block per (b, object).
// Silent predicate, division-free and qa-hoisted:
//   iou > 0.6  <=>  inter > 0.375*(pa + area)
//              <=>  max_o fmaf(iw', ih, -0.375*area_o)  >  0.375*pa
// iw is clamped to >=0; ih is NOT (if ih<0 the fma value is <=0 which can
// never exceed the positive rhs; if both<0, iw'=0 kills the false positive).
// The obj path uses the IDENTICAL fp expression form so its owner-cell
// compensation matches the cell path's decision exactly.
// ---------------------------------------------------------------------------
__global__ __launch_bounds__(BLK)
void region_kernel(const float* __restrict__ out,
                   const float* __restrict__ tgt,
                   float* __restrict__ acc) {
    __shared__ float  T[MAXOBJ*5];
    __shared__ float4 sbox[MAXOBJ];   // x1,y1,x2,y2
    __shared__ float  snthr[MAXOBJ];  // -0.375*area  (-1.0 for invalid)
    __shared__ int    keyS[MAXOBJ];
    __shared__ int    valS[MAXOBJ];
    __shared__ float  wsum[BLK/64];
    const int b = blockIdx.y;
    const int t = threadIdx.x;
    const int bid = b*GX + blockIdx.x;
    for (int i = t; i < MAXOBJ*5; i += BLK) T[i] = tgt[(size_t)b*MAXOBJ*5 + i];
    __syncthreads();

    if (blockIdx.x < NCBLK) {
        // ================= cell path =================
        if (t < MAXOBJ) {
            bool valid = true;                       // cumprod(cx>0) prefix
            for (int j2 = 0; j2 <= t; ++j2) valid = valid && (T[j2*5+1] > 0.0f);
            float gx = T[t*5+1]*NWW, gy = T[t*5+2]*NHH;
            float gw = T[t*5+3]*NWW, gh = T[t*5+4]*NHH;
            if (valid) {
                sbox[t]  = make_float4(gx - gw*0.5f, gy - gh*0.5f, gx + gw*0.5f, gy + gh*0.5f);
                snthr[t] = -0.375f*(gw*gh);
            } else {                                 // degenerate: inter==0 always
                sbox[t]  = make_float4(3e8f, 3e8f, 3e8f, 3e8f);
                snthr[t] = -1.0f;
            }
        }
        __syncthreads();

        // two aligned 4-cell groups per thread: cells c0..c0+3 and c1..c1+3
        const int cbase = blockIdx.x*CPB;
        const int cg[2] = { cbase + t*4, cbase + BLK*4 + t*4 };
        float px1[CPT], px2[CPT], py1[CPT], py2[CPT], qa[CPT], silv[CPT], cf[CPT];
        bool  liveg[2];
        #pragma unroll
        for (int g = 0; g < 2; ++g) {
            const int  c    = cg[g];
            const bool live = c < CELLS_PER_B;
            liveg[g] = live;
            // c%4==0, CSZ%4==0, NWW%4==0 -> anchor and row uniform in the group
            const int a   = c / CSZ;
            const int rem = c - a*CSZ;
            const int jj  = rem / NWW;
            const int i0  = rem - jj*NWW;
            float xr[4], yr[4], wr[4], hr[4], cc[4];
            if (live) {
                const float* base = out + ((size_t)(b*NANCH + a)*NCH)*CSZ + rem;  // 16B aligned
                float4 v;
                v = *(const float4*)(base);        xr[0]=v.x; xr[1]=v.y; xr[2]=v.z; xr[3]=v.w;
                v = *(const float4*)(base+  CSZ);  yr[0]=v.x; yr[1]=v.y; yr[2]=v.z; yr[3]=v.w;
                v = *(const float4*)(base+2*CSZ);  wr[0]=v.x; wr[1]=v.y; wr[2]=v.z; wr[3]=v.w;
                v = *(const float4*)(base+3*CSZ);  hr[0]=v.x; hr[1]=v.y; hr[2]=v.z; hr[3]=v.w;
                v = *(const float4*)(base+4*CSZ);  cc[0]=v.x; cc[1]=v.y; cc[2]=v.z; cc[3]=v.w;
            } else {
                #pragma unroll
                for (int k = 0; k < 4; ++k) { xr[k]=yr[k]=wr[k]=hr[k]=cc[k]=0.0f; }
            }
            #pragma unroll
            for (int k = 0; k < 4; ++k) {
                const int kk = g*4 + k;
                float pw = __expf(wr[k])*c_aw[a], ph = __expf(hr[k])*c_ah[a];
                float px = sigf(xr[k]) + (float)(i0 + k);
                float py = sigf(yr[k]) + (float)jj;
                px1[kk] = px - pw*0.5f; px2[kk] = px + pw*0.5f;
                py1[kk] = py - ph*0.5f; py2[kk] = py + ph*0.5f;
                qa[kk]  = 0.375f*(pw*ph);
                silv[kk] = -1e30f;
                cf[kk]  = cc[k];
            }
        }

        for (int o = 0; o < MAXOBJ; o += 2) {        // wave-uniform LDS broadcasts
            const float4 b0 = sbox[o];
            const float4 b1 = sbox[o+1];
            const float2 nt = *(const float2*)&snthr[o];
            #pragma unroll
            for (int k = 0; k < CPT; ++k) {
                float iw = fminf(px2[k], b0.z) - fmaxf(px1[k], b0.x);
                iw = fmaxf(iw, 0.0f);
                float ih = fminf(py2[k], b0.w) - fmaxf(py1[k], b0.y);
                silv[k] = fmaxf(silv[k], fmaf(iw, ih, nt.x));
            }
            #pragma unroll
            for (int k = 0; k < CPT; ++k) {
                float iw = fminf(px2[k], b1.z) - fmaxf(px1[k], b1.x);
                iw = fmaxf(iw, 0.0f);
                float ih = fminf(py2[k], b1.w) - fmaxf(py1[k], b1.y);
                silv[k] = fmaxf(silv[k], fmaf(iw, ih, nt.y));
            }
        }

        float l = 0.0f;
        #pragma unroll
        for (int g = 0; g < 2; ++g) {
            if (liveg[g]) {
                #pragma unroll
                for (int k = 0; k < 4; ++k) {
                    const int kk = g*4 + k;
                    if (!(silv[kk] > qa[kk])) {      // not silent
                        float sc = sigf(cf[kk]);
                        l += 0.5f*sc*sc;
                    }
                }
            }
        }
        for (int off = 32; off > 0; off >>= 1) l += __shfl_down(l, off);
        if ((t & 63) == 0) wsum[t >> 6] = l;
        __syncthreads();
        if (t == 0) acc[bid] = wsum[0]+wsum[1]+wsum[2]+wsum[3];

    } else {
        // ================= obj path: one block per (b, o) =================
        const int o = blockIdx.x - NCBLK;            // 0..49
        if (t < MAXOBJ) {
            bool valid = true;
            for (int j2 = 0; j2 <= t; ++j2) valid = valid && (T[j2*5+1] > 0.0f);
            valS[t] = valid ? 1 : 0;
            if (valid) {
                float gw = T[t*5+3]*NWW, gh = T[t*5+4]*NHH;
                int bn = 0; float best = -1.0f;
                for (int a = 0; a < NANCH; ++a) {    // first-max wins (argmax)
                    float inter = fminf(gw, c_aw[a]) * fminf(gh, c_ah[a]);
                    float uni   = gw*gh + c_aw[a]*c_ah[a] - inter;
                    float iou   = inter / uni;
                    if (iou > best) { best = iou; bn = a; }
                }
                int gi = (int)(T[t*5+1]*NWW), gj = (int)(T[t*5+2]*NHH);
                keyS[t] = bn*CSZ + gj*NWW + gi;
            } else keyS[t] = -1 - t;                 // unique, never matches
        }
        __syncthreads();
        if (t >= 64) return;                         // wave 0 only from here on

        float partial = 0.0f;
        const int mykey = keyS[o];
        bool owner = valS[o] != 0;                   // wave-uniform
        for (int l2 = o+1; l2 < MAXOBJ; ++l2) owner = owner && (keyS[l2] != mykey);
        if (owner) {                                 // uniform branch
            const float gx = T[o*5+1]*NWW, gy = T[o*5+2]*NHH;
            const float gw = T[o*5+3]*NWW, gh = T[o*5+4]*NHH;
            const int   cls = (int)T[o*5+0];
            const int   bn  = mykey / CSZ;
            const int   gi  = (int)gx, gj = (int)gy;
            const float* base = out + ((size_t)(b*NANCH + bn)*NCH)*CSZ + (size_t)(gj*NWW + gi);
            const float xr = base[0], yv = base[CSZ], wv = base[2*(size_t)CSZ];
            const float hv = base[3*(size_t)CSZ], cv = base[4*(size_t)CSZ];
            const float sx = sigf(xr), sy = sigf(yv), sc = sigf(cv);
            const float pw = __expf(wv)*c_aw[bn], ph = __expf(hv)*c_ah[bn];
            const float px = sx + (float)gi, py = sy + (float)gj;
            const float px1 = px - pw*0.5f, px2 = px + pw*0.5f;
            const float py1 = py - ph*0.5f, py2 = py + ph*0.5f;
            const float qa = 0.375f*(pw*ph);         // same fp form as cell path

            // silent predicate at the owner cell: lane l tests GT l
            // (identical expression form to the cell path inner loop)
            bool pred = false;
            if (t < MAXOBJ && valS[t]) {
                float ox = T[t*5+1]*NWW, oy = T[t*5+2]*NHH;
                float ow = T[t*5+3]*NWW, oh = T[t*5+4]*NHH;
                float bx1 = ox - ow*0.5f, bx2 = ox + ow*0.5f;
                float by1 = oy - oh*0.5f, by2 = oy + oh*0.5f;
                float nthr = -0.375f*(ow*oh);
                float iw = fminf(px2, bx2) - fmaxf(px1, bx1);
                iw = fmaxf(iw, 0.0f);
                float ih = fminf(py2, by2) - fmaxf(py1, by1);
                pred = fmaf(iw, ih, nthr) > qa;
            }
            const bool silent = (__ballot(pred) != 0ull);

            // class NLL: lanes parallelize the 80-logit logsumexp
            const float* lg = base + (size_t)5*CSZ;
            const float L1 = lg[(size_t)t*CSZ];
            const float L2 = (t < NCLS-64) ? lg[(size_t)(t+64)*CSZ] : -1e30f;
            float m = fmaxf(L1, L2);
            for (int off = 32; off > 0; off >>= 1) m = fmaxf(m, __shfl_xor(m, off));
            float s = __expf(L1 - m) + ((t < NCLS-64) ? __expf(L2 - m) : 0.0f);
            for (int off = 32; off > 0; off >>= 1) s += __shfl_xor(s, off);
            const float lcA = __shfl(L1, cls & 63);
            const float lcB = __shfl(L2, cls & 63);
            const float lc  = (cls < 64) ? lcA : lcB;

            if (t == 0) {
                float iw = fminf(px2, gx + gw*0.5f) - fmaxf(px1, gx - gw*0.5f);
                float ih = fminf(py2, gy + gh*0.5f) - fmaxf(py1, gy - gh*0.5f);
                iw = fmaxf(iw, 0.0f); ih = fmaxf(ih, 0.0f);
                float inter = iw*ih;
                float biou  = inter / (pw*ph + gw*gh - inter);
                float tx = gx - (float)gi, ty = gy - (float)gj;
                float tw = __logf(gw / c_aw[bn]), th = __logf(gh / c_ah[bn]);
                float l = 0.5f*((sx-tx)*(sx-tx) + (sy-ty)*(sy-ty)
                              + (wv-tw)*(wv-tw) + (hv-th)*(hv-th));     // coord
                l += 2.5f*(sc - biou)*(sc - biou);                      // obj conf
                l += m + __logf(s) - lc;                                // class NLL
                if (!silent) l -= 0.5f*sc*sc;        // undo cell path's noobj term
                partial = l;
            }
        }
        if (t == 0) acc[bid] = partial;
    }
}

// Sum the NTOT per-block partials into the scalar output.
__global__ __launch_bounds__(256)
void reduce_kernel(const float* __restrict__ acc, float* __restrict__ loss) {
    __shared__ float wsum[4];
    const int t = threadIdx.x;
    float l = 0.0f;
    for (int i = t; i < NTOT; i += 256) l += acc[i];
    for (int off = 32; off > 0; off >>= 1) l += __shfl_down(l, off);
    if ((t & 63) == 0) wsum[t >> 6] = l;
    __syncthreads();
    if (t == 0) loss[0] = wsum[0]+wsum[1]+wsum[2]+wsum[3];
}

extern "C" void kernel_launch(void* const* d_in, const int* in_sizes, int n_in,
                              void* d_out, int out_size, void* d_ws, size_t ws_size,
                              hipStream_t stream) {
    const float* out = (const float*)d_in[0];   // (32, 425, 76, 76) f32
    const float* tgt = (const float*)d_in[1];   // (32, 250) f32
    float* acc  = (float*)d_ws;                 // NTOT per-block partials
    float* loss = (float*)d_out;
    dim3 grid(GX, NBATCH);
    region_kernel<<<grid, BLK, 0, stream>>>(out, tgt, acc);
    reduce_kernel<<<1, 256, 0, stream>>>(acc, loss);
}